// Round 9
// baseline (1205.000 us; speedup 1.0000x reference)
//
#include <hip/hip_runtime.h>
#include <hip/hip_cooperative_groups.h>
#include <cstddef>
#include <cstdint>

namespace cg = cooperative_groups;

#define BATCH 32
#define NBLK 256
#define NTHR 1024
#define NT (NBLK * NTHR)

// All intermediates NODE-MAJOR [n][b][f] (addr = (n*32+b)*F + f), X4 batch-major.
// Workspace (floats):
//   Xt : 1,572,864   T : 20,971,520   X1 : 4,194,304   X2 : 1,048,576
//   X3 : 262,144     X4 : 131,072     P : 131,072      H : 4,096

struct Params {
  const float* x;
  const int* ec0; const int* ec1; const int* ec2; const int* ec3;
  const int* pc0; const int* pc1; const int* pc2; const int* pc3;
  const float* pv0; const float* pv1; const float* pv2; const float* pv3;
  const float* W0; const float* b0; const float* W1; const float* b1;
  const float* W2; const float* b2; const float* W3; const float* b3;
  const float* encW; const float* encB; const float* clsW; const float* clsB;
  float* out;
  float* Xt; float* T; float* X1; float* X2; float* X3; float* X4; float* P; float* H;
};

__device__ __forceinline__ void fma4(float4& a, float s, const float4& w) {
  a.x += s * w.x; a.y += s * w.y; a.z += s * w.z; a.w += s * w.w;
}
__device__ __forceinline__ float4 relu4(const float4& a) {
  return make_float4(fmaxf(a.x, 0.f), fmaxf(a.y, 0.f), fmaxf(a.z, 0.f), fmaxf(a.w, 0.f));
}

// ---------------- Cheb step phase (grid-stride) ----------------
template<int N, int R4>
__device__ void cheb_phase(int tid, const float4* __restrict__ Tin,
                           const float4* __restrict__ Tpp,
                           const int* __restrict__ ec, float4* __restrict__ Tout,
                           float coef, float beta)
{
  for (int idx = tid; idx < N * R4; idx += NT) {
    int n = idx / R4;
    int r = idx % R4;
    const int* e = ec + n * 6;
    float4 s = make_float4(0.f, 0.f, 0.f, 0.f);
#pragma unroll
    for (int d = 0; d < 6; ++d) {
      float4 v = Tin[(size_t)e[d] * R4 + r];
      s.x += v.x; s.y += v.y; s.z += v.z; s.w += v.w;
    }
    float4 p = Tpp[idx];
    float4 o;
    o.x = coef * s.x + beta * p.x;
    o.y = coef * s.y + beta * p.y;
    o.z = coef * s.z + beta * p.z;
    o.w = coef * s.w + beta * p.w;
    Tout[idx] = o;
  }
}

// ---------------- pool(relu(conv)) FIN=3 phase ----------------
template<int N, int M, int FOUT>
__device__ void pool_f3_phase(int tid, float* lds,
    const float* __restrict__ X, const float* __restrict__ T,
    const float* __restrict__ W, const float* __restrict__ bias,
    const int* __restrict__ pc, const float* __restrict__ pv,
    float* __restrict__ out)
{
  constexpr int F4 = FOUT / 4;
  constexpr size_t SL = (size_t)N * BATCH * 3;
  for (int i = threadIdx.x; i < 6 * 3 * FOUT; i += NTHR) lds[i] = W[i];
  __syncthreads();
  const float4* Ws4 = (const float4*)lds;
  for (int t = tid; t < M * BATCH * F4; t += NT) {
    int fo4 = t % F4;
    int b   = (t / F4) % BATCH;
    int m   = t / (F4 * BATCH);
    int c0 = pc[m * 3 + 0], c1 = pc[m * 3 + 1], c2 = pc[m * 3 + 2];
    float v0 = pv[m * 3 + 0], v1 = pv[m * 3 + 1], v2 = pv[m * 3 + 2];
    float4 bi = ((const float4*)bias)[fo4];
    float4 a0 = bi, a1 = bi, a2 = bi;
#pragma unroll
    for (int k = 0; k < 6; ++k) {
      const float* base = (k == 0) ? X : (T + (size_t)(k - 1) * SL);
      const float* r0 = base + ((size_t)c0 * BATCH + b) * 3;
      const float* r1 = base + ((size_t)c1 * BATCH + b) * 3;
      const float* r2 = base + ((size_t)c2 * BATCH + b) * 3;
#pragma unroll
      for (int f = 0; f < 3; ++f) {
        float4 w = Ws4[(k * 3 + f) * F4 + fo4];
        fma4(a0, r0[f], w);
        fma4(a1, r1[f], w);
        fma4(a2, r2[f], w);
      }
    }
    a0 = relu4(a0); a1 = relu4(a1); a2 = relu4(a2);
    float4 acc;
    acc.x = v0*a0.x + v1*a1.x + v2*a2.x;
    acc.y = v0*a0.y + v1*a1.y + v2*a2.y;
    acc.z = v0*a0.z + v1*a1.z + v2*a2.z;
    acc.w = v0*a0.w + v1*a1.w + v2*a2.w;
    ((float4*)out)[t] = acc;   // node-major [m][b][fo]
  }
}

// ---------------- pool(relu(conv)) FIN=32 phase, node-major T ----------------
template<int N, int M, int FOUT, bool OUT_BM>
__device__ void pool_v32_phase(int tid, float* lds,
    const float* __restrict__ X, const float* __restrict__ T,
    const float* __restrict__ W, const float* __restrict__ bias,
    const int* __restrict__ pc, const float* __restrict__ pv,
    float* __restrict__ out)
{
  constexpr int F4 = FOUT / 4;
  constexpr size_t SL4 = (size_t)N * BATCH * 32 / 4;   // slice stride (float4)
  for (int i = threadIdx.x; i < 6 * 32 * FOUT; i += NTHR) lds[i] = W[i];
  __syncthreads();
  const float4* Ws4 = (const float4*)lds;
  const float4* X4p = (const float4*)X;
  const float4* T4s = (const float4*)T;
  for (int t = tid; t < M * BATCH * F4; t += NT) {
    int fo4 = t % F4;
    int b   = (t / F4) % BATCH;
    int m   = t / (F4 * BATCH);
    int c0 = pc[m * 3 + 0], c1 = pc[m * 3 + 1], c2 = pc[m * 3 + 2];
    float v0 = pv[m * 3 + 0], v1 = pv[m * 3 + 1], v2 = pv[m * 3 + 2];
    float4 bi = ((const float4*)bias)[fo4];
    float4 a0 = bi, a1 = bi, a2 = bi;
#pragma unroll 1
    for (int k = 0; k < 6; ++k) {
      const float4* base = (k == 0) ? X4p : (T4s + (size_t)(k - 1) * SL4);
      const float4* r0 = base + ((size_t)c0 * BATCH + b) * 8;
      const float4* r1 = base + ((size_t)c1 * BATCH + b) * 8;
      const float4* r2 = base + ((size_t)c2 * BATCH + b) * 8;
#pragma unroll
      for (int fi = 0; fi < 8; ++fi) {
        float4 t0 = r0[fi], t1 = r1[fi], t2 = r2[fi];
#pragma unroll
        for (int ff = 0; ff < 4; ++ff) {
          float4 w = Ws4[((k * 32) + fi * 4 + ff) * F4 + fo4];
          fma4(a0, ((const float*)&t0)[ff], w);
          fma4(a1, ((const float*)&t1)[ff], w);
          fma4(a2, ((const float*)&t2)[ff], w);
        }
      }
    }
    a0 = relu4(a0); a1 = relu4(a1); a2 = relu4(a2);
    float4 acc;
    acc.x = v0*a0.x + v1*a1.x + v2*a2.x;
    acc.y = v0*a0.y + v1*a1.y + v2*a2.y;
    acc.z = v0*a0.z + v1*a1.z + v2*a2.z;
    acc.w = v0*a0.w + v1*a1.w + v2*a2.w;
    size_t oi = OUT_BM ? (((size_t)b * M + m) * F4 + fo4) : ((size_t)t);
    ((float4*)out)[oi] = acc;
  }
}

// ---------------- the mega kernel ----------------
__global__ void __launch_bounds__(NTHR, 4) cheb_mega(Params P_)
{
  cg::grid_group grid = cg::this_grid();
  __shared__ float lds[12288];            // 48 KB, reused by pool phases
  const int tid = blockIdx.x * NTHR + threadIdx.x;
  const float cI = -1.0f / 6.0f;
  const float cS = -1.0f / 3.0f;

  // phase: transpose x[b][n][3] -> Xt[n][b][3]
  for (int t = tid; t < 16384 * 96; t += NT) {
    int n = t / 96;
    int r = t % 96;
    int b = r / 3;
    int f = r - b * 3;
    P_.Xt[t] = P_.x[((size_t)b * 16384 + n) * 3 + f];
  }
  grid.sync();

  // ========== layer 0: N=16384, R4=24 ==========
  {
    constexpr size_t S4 = (size_t)16384 * 24;   // slice stride in float4
    const float4* Xt4 = (const float4*)P_.Xt;
    float4* T4 = (float4*)P_.T;
    cheb_phase<16384, 24>(tid, Xt4,      Xt4,      P_.ec0, T4,          cI,  0.f); grid.sync();
    cheb_phase<16384, 24>(tid, T4,       Xt4,      P_.ec0, T4 + S4,     cS, -1.f); grid.sync();
    cheb_phase<16384, 24>(tid, T4 + S4,  T4,       P_.ec0, T4 + 2*S4,   cS, -1.f); grid.sync();
    cheb_phase<16384, 24>(tid, T4 + 2*S4, T4 + S4, P_.ec0, T4 + 3*S4,   cS, -1.f); grid.sync();
    cheb_phase<16384, 24>(tid, T4 + 3*S4, T4 + 2*S4, P_.ec0, T4 + 4*S4, cS, -1.f); grid.sync();
    pool_f3_phase<16384, 4096, 32>(tid, lds, P_.Xt, P_.T, P_.W0, P_.b0, P_.pc0, P_.pv0, P_.X1);
    grid.sync();
  }
  // ========== layer 1: N=4096, R4=256 ==========
  {
    constexpr size_t S4 = (size_t)4096 * 256;
    const float4* X14 = (const float4*)P_.X1;
    float4* T4 = (float4*)P_.T;
    cheb_phase<4096, 256>(tid, X14,       X14,      P_.ec1, T4,        cI,  0.f); grid.sync();
    cheb_phase<4096, 256>(tid, T4,        X14,      P_.ec1, T4 + S4,   cS, -1.f); grid.sync();
    cheb_phase<4096, 256>(tid, T4 + S4,   T4,       P_.ec1, T4 + 2*S4, cS, -1.f); grid.sync();
    cheb_phase<4096, 256>(tid, T4 + 2*S4, T4 + S4,  P_.ec1, T4 + 3*S4, cS, -1.f); grid.sync();
    cheb_phase<4096, 256>(tid, T4 + 3*S4, T4 + 2*S4, P_.ec1, T4 + 4*S4, cS, -1.f); grid.sync();
    pool_v32_phase<4096, 1024, 32, false>(tid, lds, P_.X1, P_.T, P_.W1, P_.b1, P_.pc1, P_.pv1, P_.X2);
    grid.sync();
  }
  // ========== layer 2: N=1024, R4=256 ==========
  {
    constexpr size_t S4 = (size_t)1024 * 256;
    const float4* X24 = (const float4*)P_.X2;
    float4* T4 = (float4*)P_.T;
    cheb_phase<1024, 256>(tid, X24,       X24,      P_.ec2, T4,        cI,  0.f); grid.sync();
    cheb_phase<1024, 256>(tid, T4,        X24,      P_.ec2, T4 + S4,   cS, -1.f); grid.sync();
    cheb_phase<1024, 256>(tid, T4 + S4,   T4,       P_.ec2, T4 + 2*S4, cS, -1.f); grid.sync();
    cheb_phase<1024, 256>(tid, T4 + 2*S4, T4 + S4,  P_.ec2, T4 + 3*S4, cS, -1.f); grid.sync();
    cheb_phase<1024, 256>(tid, T4 + 3*S4, T4 + 2*S4, P_.ec2, T4 + 4*S4, cS, -1.f); grid.sync();
    pool_v32_phase<1024, 256, 32, false>(tid, lds, P_.X2, P_.T, P_.W2, P_.b2, P_.pc2, P_.pv2, P_.X3);
    grid.sync();
  }
  // ========== layer 3: N=256, R4=256, FOUT=64, batch-major out ==========
  {
    constexpr size_t S4 = (size_t)256 * 256;
    const float4* X34 = (const float4*)P_.X3;
    float4* T4 = (float4*)P_.T;
    cheb_phase<256, 256>(tid, X34,       X34,      P_.ec3, T4,        cI,  0.f); grid.sync();
    cheb_phase<256, 256>(tid, T4,        X34,      P_.ec3, T4 + S4,   cS, -1.f); grid.sync();
    cheb_phase<256, 256>(tid, T4 + S4,   T4,       P_.ec3, T4 + 2*S4, cS, -1.f); grid.sync();
    cheb_phase<256, 256>(tid, T4 + 2*S4, T4 + S4,  P_.ec3, T4 + 3*S4, cS, -1.f); grid.sync();
    cheb_phase<256, 256>(tid, T4 + 3*S4, T4 + 2*S4, P_.ec3, T4 + 4*S4, cS, -1.f); grid.sync();
    pool_v32_phase<256, 64, 64, true>(tid, lds, P_.X3, P_.T, P_.W3, P_.b3, P_.pc3, P_.pv3, P_.X4);
    grid.sync();
  }
  // ========== head ==========
  // encoder split-K partials: P[b][chunk][fo], 32 chunks of 128 rows
  for (int t = tid; t < 32 * 32 * 128; t += NT) {
    int fo    = t & 127;
    int chunk = (t >> 7) & 31;
    int b     = t >> 12;
    const float* xr = P_.X4 + b * 4096 + chunk * 128;
    const float* w  = P_.encW + (size_t)(chunk * 128) * 128 + fo;
    float acc = 0.f;
#pragma unroll 8
    for (int i = 0; i < 128; ++i) acc += xr[i] * w[(size_t)i * 128];
    P_.P[t] = acc;
  }
  grid.sync();
  // H[b][fo] = relu(sum_chunks + bias)
  for (int t = tid; t < 32 * 128; t += NT) {
    int b = t >> 7, fo = t & 127;
    float acc = P_.encB[fo];
#pragma unroll
    for (int c = 0; c < 32; ++c) acc += P_.P[((b * 32 + c) << 7) + fo];
    P_.H[t] = fmaxf(acc, 0.f);
  }
  grid.sync();
  // classifier
  for (int t = tid; t < 320; t += NT) {
    int b = t / 10, c = t % 10;
    float acc = P_.clsB[c];
#pragma unroll 4
    for (int f = 0; f < 128; ++f) acc += P_.H[b * 128 + f] * P_.clsW[f * 10 + c];
    P_.out[t] = acc;
  }
}

extern "C" void kernel_launch(void* const* d_in, const int* in_sizes, int n_in,
                              void* d_out, int out_size, void* d_ws, size_t ws_size,
                              hipStream_t stream)
{
  float* ws = (float*)d_ws;
  Params p;
  p.x   = (const float*)d_in[0];
  p.ec0 = (const int*)d_in[2];
  p.ec1 = (const int*)d_in[4];
  p.ec2 = (const int*)d_in[6];
  p.ec3 = (const int*)d_in[8];
  p.pc0 = (const int*)d_in[10]; p.pv0 = (const float*)d_in[11];
  p.pc1 = (const int*)d_in[13]; p.pv1 = (const float*)d_in[14];
  p.pc2 = (const int*)d_in[16]; p.pv2 = (const float*)d_in[17];
  p.pc3 = (const int*)d_in[19]; p.pv3 = (const float*)d_in[20];
  p.W0 = (const float*)d_in[21]; p.b0 = (const float*)d_in[22];
  p.W1 = (const float*)d_in[23]; p.b1 = (const float*)d_in[24];
  p.W2 = (const float*)d_in[25]; p.b2 = (const float*)d_in[26];
  p.W3 = (const float*)d_in[27]; p.b3 = (const float*)d_in[28];
  p.encW = (const float*)d_in[29]; p.encB = (const float*)d_in[30];
  p.clsW = (const float*)d_in[31]; p.clsB = (const float*)d_in[32];
  p.out = (float*)d_out;
  p.Xt = ws;                       // 1,572,864
  p.T  = p.Xt + 1572864;           // 20,971,520
  p.X1 = p.T  + 20971520;          // 4,194,304
  p.X2 = p.X1 + 4194304;           // 1,048,576
  p.X3 = p.X2 + 1048576;           // 262,144
  p.X4 = p.X3 + 262144;            // 131,072
  p.P  = p.X4 + 131072;            // 131,072
  p.H  = p.P  + 131072;            // 4,096

  void* args[] = {&p};
  hipLaunchCooperativeKernel((void*)cheb_mega, dim3(NBLK), dim3(NTHR),
                             args, 0, stream);
}

// Round 10
// 326.428 us; speedup vs baseline: 3.6915x; 3.6915x over previous
//
#include <hip/hip_runtime.h>
#include <cstddef>
#include <cstdint>

#define BATCH 32

// All intermediates are NODE-MAJOR: X[n][b][f]  (addr = (n*32 + b)*F + f).
// Workspace (floats):
//   Xt : 1,572,864   (transposed input, [16384][32][3])
//   T  : 20,971,520  (T1..T5; max slice = layer1: 4096*32*32 = 4,194,304)
//   X1 : 4,194,304   ([4096][32][32])
//   X2 : 1,048,576   ([1024][32][32])
//   X3 : 262,144     ([256][32][32])
//   X4 : 131,072     ([32][4096] batch-major for encoder)
//   P  : 65,536      (encoder split-K partials)

__device__ __forceinline__ void fma4(float4& a, float s, const float4& w) {
  a.x += s * w.x; a.y += s * w.y; a.z += s * w.z; a.w += s * w.w;
}
__device__ __forceinline__ float4 relu4(const float4& a) {
  return make_float4(fmaxf(a.x, 0.f), fmaxf(a.y, 0.f), fmaxf(a.z, 0.f), fmaxf(a.w, 0.f));
}

// ---------------- transpose x[b][n][3] -> Xt[n][b][3] ----------------
__global__ void __launch_bounds__(256) transpose_x(
    const float* __restrict__ x, float* __restrict__ xt)
{
  int t = blockIdx.x * 256 + threadIdx.x;     // n*96 + b*3 + f
  int n = t / 96;
  int r = t % 96;
  int b = r / 3;
  int f = r - b * 3;
  xt[t] = x[((size_t)b * 16384 + n) * 3 + f];
}

// ---------------- node-major Cheb step (layer 0 only) ----------------
template<int N, int R4>
__global__ void __launch_bounds__(256) cheb_step_nm(
    const float4* __restrict__ Tin, const float4* __restrict__ Tpp,
    const int* __restrict__ ec, float4* __restrict__ Tout,
    float coef, float beta)
{
  int idx = blockIdx.x * 256 + threadIdx.x;   // exact grid: N*R4 threads
  int n = idx / R4;
  int r = idx % R4;
  const int* e = ec + n * 6;
  float4 s = make_float4(0.f, 0.f, 0.f, 0.f);
#pragma unroll
  for (int d = 0; d < 6; ++d) {
    float4 v = Tin[(size_t)e[d] * R4 + r];
    s.x += v.x; s.y += v.y; s.z += v.z; s.w += v.w;
  }
  float4 p = Tpp[idx];
  float4 o;
  o.x = coef * s.x + beta * p.x;
  o.y = coef * s.y + beta * p.y;
  o.z = coef * s.z + beta * p.z;
  o.w = coef * s.w + beta * p.w;
  Tout[idx] = o;
}

// ---------------- LDS-resident Chebyshev recurrence v3 (layers 1-3) ----------------
// Block = (b, f-slab of FS=2). One LDS buffer holds T_{k-1}[all n][FS];
// T_{k-2} in registers (prevv). After the gather barrier, the thread's own
// LDS slot still holds T_{k-1} -> re-read it as the new prev (no curv array:
// this is what kept R7 under the VGPR cap... it didn't; MINW=4 now does).
template<int N, int F, int THREADS, int MINW>
__global__ void __launch_bounds__(THREADS, MINW) cheb_recur_reg(
    const float* __restrict__ X,    // node-major [N][32][F]
    const int* __restrict__ ec,     // [N][6]
    float* __restrict__ T)          // 5 slices, node-major
{
  constexpr int FS = 2;
  constexpr int NPT = N / THREADS;             // nodes per thread
  __shared__ float cur[N * FS];
  const float cI = -1.0f / 6.0f;
  const float cS = -1.0f / 3.0f;
  const int b = blockIdx.x & 31;
  const int fbase = (blockIdx.x >> 5) * FS;
  constexpr size_t SL = (size_t)N * 32 * F;    // slice stride (floats)
  float prevv[NPT][FS];                        // T_{k-2} at owned nodes
  // load T0 slab
#pragma unroll
  for (int i = 0; i < NPT; ++i) {
    int n = threadIdx.x + i * THREADS;
    float2 v = *(const float2*)(X + ((size_t)n * 32 + b) * F + fbase);
    cur[n * FS + 0] = v.x;
    cur[n * FS + 1] = v.y;
  }
  __syncthreads();
#pragma unroll 1
  for (int k = 1; k <= 5; ++k) {
    float newv[NPT][FS];
    float* Tk = T + (size_t)(k - 1) * SL;
#pragma unroll
    for (int i = 0; i < NPT; ++i) {
      int n = threadIdx.x + i * THREADS;
      const int* e = ec + n * 6;
      float s0 = 0.f, s1 = 0.f;
#pragma unroll
      for (int d = 0; d < 6; ++d) {
        int c = e[d];
        s0 += cur[c * FS + 0];
        s1 += cur[c * FS + 1];
      }
      float v0, v1;
      if (k == 1) { v0 = cI * s0; v1 = cI * s1; }
      else        { v0 = cS * s0 - prevv[i][0]; v1 = cS * s1 - prevv[i][1]; }
      newv[i][0] = v0; newv[i][1] = v1;
      *(float2*)(Tk + ((size_t)n * 32 + b) * F + fbase) = make_float2(v0, v1);
    }
    __syncthreads();   // all gathers of T_{k-1} complete
#pragma unroll
    for (int i = 0; i < NPT; ++i) {
      int n = threadIdx.x + i * THREADS;
      prevv[i][0] = cur[n * FS + 0];           // own slot still = T_{k-1}
      prevv[i][1] = cur[n * FS + 1];
      cur[n * FS + 0] = newv[i][0];            // T_k -> cur
      cur[n * FS + 1] = newv[i][1];
    }
    __syncthreads();
  }
}

// ---------------- fused pool(relu(conv)), FIN=3, materialized T1..T5 ----------------
template<int N, int M, int FOUT, bool OUT_BM>
__global__ void __launch_bounds__(256) pool_conv_f3(
    const float* __restrict__ X, const float* __restrict__ T,
    const float* __restrict__ W, const float* __restrict__ bias,
    const int* __restrict__ pc, const float* __restrict__ pv,
    float* __restrict__ out)
{
  constexpr int F4 = FOUT / 4;
  constexpr size_t SL = (size_t)N * BATCH * 3;   // slice stride (floats)
  __shared__ float Ws[6 * 3 * FOUT];
  for (int i = threadIdx.x; i < 6 * 3 * FOUT; i += 256) Ws[i] = W[i];
  __syncthreads();
  const float4* Ws4 = (const float4*)Ws;
  int t = blockIdx.x * 256 + threadIdx.x;     // exact grid: M*32*F4
  int fo4 = t % F4;
  int b   = (t / F4) % BATCH;
  int m   = t / (F4 * BATCH);
  int c0 = pc[m * 3 + 0], c1 = pc[m * 3 + 1], c2 = pc[m * 3 + 2];
  float v0 = pv[m * 3 + 0], v1 = pv[m * 3 + 1], v2 = pv[m * 3 + 2];
  float4 bi = ((const float4*)bias)[fo4];
  float4 a0 = bi, a1 = bi, a2 = bi;
#pragma unroll
  for (int k = 0; k < 6; ++k) {
    const float* base = (k == 0) ? X : (T + (size_t)(k - 1) * SL);
    const float* r0 = base + ((size_t)c0 * BATCH + b) * 3;
    const float* r1 = base + ((size_t)c1 * BATCH + b) * 3;
    const float* r2 = base + ((size_t)c2 * BATCH + b) * 3;
#pragma unroll
    for (int f = 0; f < 3; ++f) {
      float4 w = Ws4[(k * 3 + f) * F4 + fo4];
      fma4(a0, r0[f], w);
      fma4(a1, r1[f], w);
      fma4(a2, r2[f], w);
    }
  }
  a0 = relu4(a0); a1 = relu4(a1); a2 = relu4(a2);
  float4 acc;
  acc.x = v0*a0.x + v1*a1.x + v2*a2.x;
  acc.y = v0*a0.y + v1*a1.y + v2*a2.y;
  acc.z = v0*a0.z + v1*a1.z + v2*a2.z;
  acc.w = v0*a0.w + v1*a1.w + v2*a2.w;
  size_t oi = OUT_BM ? (((size_t)b * M + m) * F4 + fo4) : (((size_t)m * BATCH + b) * F4 + fo4);
  ((float4*)out)[oi] = acc;
}

// ---------------- fused pool(relu(conv)), FIN=32, node-major T ----------------
template<int N, int M, int FOUT, bool OUT_BM>
__global__ void __launch_bounds__(256) pool_conv_v32(
    const float* __restrict__ X, const float* __restrict__ T,
    const float* __restrict__ W, const float* __restrict__ bias,
    const int* __restrict__ pc, const float* __restrict__ pv,
    float* __restrict__ out)
{
  constexpr int FIN = 32;
  constexpr int F4 = FOUT / 4;
  constexpr size_t SL4 = (size_t)N * BATCH * FIN / 4;   // slice stride (float4)
  __shared__ float Ws[6 * FIN * FOUT];                  // 24 KB or 48 KB
  for (int i = threadIdx.x; i < 6 * FIN * FOUT; i += 256) Ws[i] = W[i];
  __syncthreads();
  const float4* Ws4 = (const float4*)Ws;
  const float4* X4p = (const float4*)X;
  const float4* T4s = (const float4*)T;
  int t = blockIdx.x * 256 + threadIdx.x;     // exact grid: M*32*F4
  int fo4 = t % F4;
  int b   = (t / F4) % BATCH;
  int m   = t / (F4 * BATCH);
  int c0 = pc[m * 3 + 0], c1 = pc[m * 3 + 1], c2 = pc[m * 3 + 2];
  float v0 = pv[m * 3 + 0], v1 = pv[m * 3 + 1], v2 = pv[m * 3 + 2];
  float4 bi = ((const float4*)bias)[fo4];
  float4 a0 = bi, a1 = bi, a2 = bi;
#pragma unroll 1
  for (int k = 0; k < 6; ++k) {
    const float4* base = (k == 0) ? X4p : (T4s + (size_t)(k - 1) * SL4);
    const float4* r0 = base + ((size_t)c0 * BATCH + b) * 8;
    const float4* r1 = base + ((size_t)c1 * BATCH + b) * 8;
    const float4* r2 = base + ((size_t)c2 * BATCH + b) * 8;
#pragma unroll
    for (int fi = 0; fi < 8; ++fi) {
      float4 t0 = r0[fi], t1 = r1[fi], t2 = r2[fi];
#pragma unroll
      for (int ff = 0; ff < 4; ++ff) {
        float4 w = Ws4[((k * 32) + fi * 4 + ff) * F4 + fo4];
        fma4(a0, ((const float*)&t0)[ff], w);
        fma4(a1, ((const float*)&t1)[ff], w);
        fma4(a2, ((const float*)&t2)[ff], w);
      }
    }
  }
  a0 = relu4(a0); a1 = relu4(a1); a2 = relu4(a2);
  float4 acc;
  acc.x = v0*a0.x + v1*a1.x + v2*a2.x;
  acc.y = v0*a0.y + v1*a1.y + v2*a2.y;
  acc.z = v0*a0.z + v1*a1.z + v2*a2.z;
  acc.w = v0*a0.w + v1*a1.w + v2*a2.w;
  size_t oi = OUT_BM ? (((size_t)b * M + m) * F4 + fo4) : (((size_t)m * BATCH + b) * F4 + fo4);
  ((float4*)out)[oi] = acc;
}

// ---------------- encoder split-K partial ----------------
__global__ void __launch_bounds__(256) encoder_partial(
    const float* __restrict__ Xf, const float* __restrict__ encW,
    float* __restrict__ partial)
{
  int b  = blockIdx.x;        // 0..31
  int ks = blockIdx.y;        // 0..15
  int fo = threadIdx.x & 127;
  int half = threadIdx.x >> 7;
  const float* xr = Xf + b * 4096 + ks * 256 + half * 128;
  const float* w  = encW + (size_t)(ks * 256 + half * 128) * 128;
  float acc = 0.f;
#pragma unroll 8
  for (int i = 0; i < 128; ++i) acc += xr[i] * w[(size_t)i * 128 + fo];
  __shared__ float part[256];
  part[threadIdx.x] = acc;
  __syncthreads();
  if (half == 0) partial[(size_t)(b * 16 + ks) * 128 + fo] = part[fo] + part[128 + fo];
}

// ---------------- fused encoder-reduce + relu + classifier ----------------
__global__ void __launch_bounds__(128) encoder_reduce_cls(
    const float* __restrict__ partial, const float* __restrict__ encB,
    const float* __restrict__ clsW, const float* __restrict__ clsB,
    float* __restrict__ out)
{
  int b = blockIdx.x;           // 0..31
  int fo = threadIdx.x;         // 0..127
  float acc = encB[fo];
#pragma unroll
  for (int ks = 0; ks < 16; ++ks) acc += partial[(size_t)(b * 16 + ks) * 128 + fo];
  __shared__ float Hs[128];
  Hs[fo] = fmaxf(acc, 0.f);
  __syncthreads();
  if (fo < 10) {
    float s = clsB[fo];
#pragma unroll 4
    for (int f = 0; f < 128; ++f) s += Hs[f] * clsW[f * 10 + fo];
    out[b * 10 + fo] = s;
  }
}

extern "C" void kernel_launch(void* const* d_in, const int* in_sizes, int n_in,
                              void* d_out, int out_size, void* d_ws, size_t ws_size,
                              hipStream_t stream)
{
  const float* x   = (const float*)d_in[0];
  const int* ec0 = (const int*)d_in[2];
  const int* ec1 = (const int*)d_in[4];
  const int* ec2 = (const int*)d_in[6];
  const int* ec3 = (const int*)d_in[8];
  const int* pc0 = (const int*)d_in[10]; const float* pv0 = (const float*)d_in[11];
  const int* pc1 = (const int*)d_in[13]; const float* pv1 = (const float*)d_in[14];
  const int* pc2 = (const int*)d_in[16]; const float* pv2 = (const float*)d_in[17];
  const int* pc3 = (const int*)d_in[19]; const float* pv3 = (const float*)d_in[20];
  const float* W0 = (const float*)d_in[21]; const float* b0 = (const float*)d_in[22];
  const float* W1 = (const float*)d_in[23]; const float* b1 = (const float*)d_in[24];
  const float* W2 = (const float*)d_in[25]; const float* b2 = (const float*)d_in[26];
  const float* W3 = (const float*)d_in[27]; const float* b3 = (const float*)d_in[28];
  const float* encW = (const float*)d_in[29]; const float* encB = (const float*)d_in[30];
  const float* clsW = (const float*)d_in[31]; const float* clsB = (const float*)d_in[32];
  float* out = (float*)d_out;

  float* ws = (float*)d_ws;
  float* Xt = ws;                       // 1,572,864
  float* T  = Xt + 1572864;             // 20,971,520 (T1..T5, layer-1 sized)
  float* X1 = T  + 20971520;            // 4,194,304
  float* X2 = X1 + 4194304;             // 1,048,576
  float* X3 = X2 + 1048576;             // 262,144
  float* X4 = X3 + 262144;              // 131,072  ([32][4096])
  float* P  = X4 + 131072;              // 65,536

  const float cI = -1.0f / 6.0f;
  const float cS = -1.0f / 3.0f;
  dim3 blk(256);

  transpose_x<<<dim3(6144), blk, 0, stream>>>(x, Xt);

  // ================= layer 0: N=16384, R=96 (R4=24), M=4096 =================
  {
    constexpr size_t S = (size_t)16384 * 96;   // slice floats
    const float4* Xt4 = (const float4*)Xt;
    cheb_step_nm<16384, 24><<<dim3(1536), blk, 0, stream>>>(
        Xt4, Xt4, ec0, (float4*)T, cI, 0.f);
    cheb_step_nm<16384, 24><<<dim3(1536), blk, 0, stream>>>(
        (const float4*)T, Xt4, ec0, (float4*)(T + S), cS, -1.f);
    cheb_step_nm<16384, 24><<<dim3(1536), blk, 0, stream>>>(
        (const float4*)(T + S), (const float4*)T, ec0, (float4*)(T + 2 * S), cS, -1.f);
    cheb_step_nm<16384, 24><<<dim3(1536), blk, 0, stream>>>(
        (const float4*)(T + 2 * S), (const float4*)(T + S), ec0, (float4*)(T + 3 * S), cS, -1.f);
    cheb_step_nm<16384, 24><<<dim3(1536), blk, 0, stream>>>(
        (const float4*)(T + 3 * S), (const float4*)(T + 2 * S), ec0, (float4*)(T + 4 * S), cS, -1.f);
    pool_conv_f3<16384, 4096, 32, false><<<dim3(4096), blk, 0, stream>>>(
        Xt, T, W0, b0, pc0, pv0, X1);
  }
  // ================= layer 1: N=4096, F=32, M=1024 =================
  // 512 blocks (32 b x 16 slabs) x 512 thr, 32 KB LDS, MINW=4 (128-VGPR cap,
  // no spill; R7's (1024,8) forced 64-VGPR spill -> 90 MB scratch traffic).
  {
    cheb_recur_reg<4096, 32, 512, 4><<<dim3(512), dim3(512), 0, stream>>>(X1, ec1, T);
    pool_conv_v32<4096, 1024, 32, false><<<dim3(1024), blk, 0, stream>>>(
        X1, T, W1, b1, pc1, pv1, X2);
  }
  // ================= layer 2: N=1024, F=32, M=256 =================
  {
    cheb_recur_reg<1024, 32, 256, 4><<<dim3(512), blk, 0, stream>>>(X2, ec2, T);
    pool_conv_v32<1024, 256, 32, false><<<dim3(256), blk, 0, stream>>>(
        X2, T, W2, b2, pc2, pv2, X3);
  }
  // ================= layer 3: N=256, F=32, M=64, FOUT=64, batch-major out =================
  {
    cheb_recur_reg<256, 32, 256, 4><<<dim3(512), blk, 0, stream>>>(X3, ec3, T);
    pool_conv_v32<256, 64, 64, true><<<dim3(128), blk, 0, stream>>>(
        X3, T, W3, b3, pc3, pv3, X4);
  }
  // ================= head =================
  encoder_partial<<<dim3(32, 16), blk, 0, stream>>>(X4, encW, P);
  encoder_reduce_cls<<<dim3(32), dim3(128), 0, stream>>>(P, encB, clsW, clsB, out);
}